// Round 1
// baseline (349.467 us; speedup 1.0000x reference)
//
#include <hip/hip_runtime.h>
#include <math.h>

// Geometric BA (LM) — 4 iterations, B=8, N=131072.
// Structure per iteration:
//   kupdate  : (it==0) init pose/L/flags; else reduce r1/r2 partials -> accept M,
//              update pose_cur/L/flags
//   kpassA   : per-point Jacobians; reduce Bm(21)+g(6)+Hsc(21)+bsc(6)=54/batch.
//              Also performs disp select-on-read (flag ? prop : cur) + writeback.
//   ksolve   : per-batch 6x6 preconditioned solve + SE3 exp + pose compose
//   kpassB   : per-point delta-disp -> clipped proposal; reduce r1/r2/masksum
// final: kupdate(4) -> flags/pose select; kout writes pose + selected disp.
//
// disp_cur lives in d_out+128 (the output disp region) to save workspace.

constexpr int TPB  = 256;
constexpr int BLKA = 64;   // blocks per batch for the big per-point kernels
constexpr int NRED = 54;   // Bm(21) + g(6) + Hsc(21) + bsc(6)

__device__ __forceinline__ float wave_red(float v) {
#pragma unroll
  for (int m = 32; m; m >>= 1) v += __shfl_xor(v, m, 64);
  return v;
}

__device__ __forceinline__ float reproj_norm(
    float x1, float y1, float x2, float y2, float d,
    const float* P, const float* Kc, const float* Ki) {
  float depth = 1.0f / fmaxf(d, 0.01f);
  float pxx = (Ki[0]*x1 + Ki[1]*y1 + Ki[2]) * depth;
  float pyy = (Ki[3]*x1 + Ki[4]*y1 + Ki[5]) * depth;
  float pzz = (Ki[6]*x1 + Ki[7]*y1 + Ki[8]) * depth;
  float X = P[0]*pxx + P[1]*pyy + P[2]*pzz + P[3];
  float Y = P[4]*pxx + P[5]*pyy + P[6]*pzz + P[7];
  float Z = P[8]*pxx + P[9]*pyy + P[10]*pzz + P[11];
  float q0 = Kc[0]*X + Kc[1]*Y + Kc[2]*Z;
  float q1 = Kc[3]*X + Kc[4]*Y + Kc[5]*Z;
  float q2 = Kc[6]*X + Kc[7]*Y + Kc[8]*Z;
  float iZc = 1.0f / fmaxf(q2, 0.01f);
  float ex = x2 - q0*iZc, ey = y2 - q1*iZc;
  return sqrtf(ex*ex + ey*ey);
}

// ---------------- Pass A: Jacobians + 54-value reduction ----------------
__global__ __launch_bounds__(TPB) void kpassA(
    const float* __restrict__ pts, const float* __restrict__ disp_src,
    const float* __restrict__ prop, const float* __restrict__ mask,
    const float* __restrict__ Kin, const float* __restrict__ Kiin,
    float* __restrict__ disp_cur, const float* __restrict__ pose_cur,
    const float* __restrict__ Lc, const float* __restrict__ flags,
    float* __restrict__ partA, int N) {
  const int b = blockIdx.y;
  float Kc[9], Ki[9], P[12];
#pragma unroll
  for (int i = 0; i < 9; i++) { Kc[i] = Kin[b*9+i]; Ki[i] = Kiin[b*9+i]; }
#pragma unroll
  for (int i = 0; i < 12; i++) P[i] = pose_cur[b*16+i];
  const float Lval = Lc[b];
  const float onepL = 1.0f + Lval;
  const float fsel = flags[b];
  const float fx = Kc[0], fy = Kc[4];

  float acc[NRED];
#pragma unroll
  for (int k = 0; k < NRED; k++) acc[k] = 0.0f;

  const size_t bN = (size_t)b * N;
  const float* px1 = pts + (size_t)b*4*N;
  const float* py1 = px1 + N;
  const float* px2 = px1 + 2*(size_t)N;
  const float* py2 = px1 + 3*(size_t)N;

  for (int n = blockIdx.x*TPB + threadIdx.x; n < N; n += gridDim.x*TPB) {
    float x1 = px1[n], y1 = py1[n], x2 = px2[n], y2 = py2[n];
    float d = disp_src[bN+n];
    if (fsel != 0.0f) d = prop[bN+n];
    disp_cur[bN+n] = d;            // authoritative entry disp for this iter
    float m = mask[bN+n];

    float depth = 1.0f / d;        // reference: pts_depth = 1/pts_disp (no clamp)
    float pxx = (Ki[0]*x1 + Ki[1]*y1 + Ki[2]) * depth;
    float pyy = (Ki[3]*x1 + Ki[4]*y1 + Ki[5]) * depth;
    float pzz = (Ki[6]*x1 + Ki[7]*y1 + Ki[8]) * depth;
    float X = P[0]*pxx + P[1]*pyy + P[2]*pzz + P[3];
    float Y = P[4]*pxx + P[5]*pyy + P[6]*pzz + P[7];
    float Z = P[8]*pxx + P[9]*pyy + P[10]*pzz + P[11];
    float q0 = Kc[0]*X + Kc[1]*Y + Kc[2]*Z;
    float q1 = Kc[3]*X + Kc[4]*Y + Kc[5]*Z;
    float q2 = Kc[6]*X + Kc[7]*Y + Kc[8]*Z;
    float iZc = 1.0f / fmaxf(q2, 0.01f);
    float ex = x2 - q0*iZc;
    float ey = y2 - q1*iZc;
    float iZ = 1.0f / fmaxf(Z, 1e-12f);
    float iZ2 = iZ*iZ;

    float jp0[6], jp1[6];
    jp0[0] = -(fx*iZ);  jp0[1] = 0.0f;       jp0[2] = fx*X*iZ2;
    jp0[3] = fx*X*Y*iZ2; jp0[4] = -(fx + fx*X*X*iZ2); jp0[5] = fx*Y*iZ;
    jp1[0] = 0.0f;      jp1[1] = -(fy*iZ);   jp1[2] = fy*Y*iZ2;
    jp1[3] = fy + fy*Y*Y*iZ2; jp1[4] = -(fy*X*Y*iZ2); jp1[5] = -(fy*X*iZ);

    float DD = -depth;            // -1/d
    float dx = X - P[3], dy = Y - P[7], dz = Z - P[11];
    float jd0 = -((fx*iZ)*(DD*dx) - (fx*X*iZ2)*(DD*dz));
    float jd1 = -((fy*iZ)*(DD*dy) - (fy*Y*iZ2)*(DD*dz));

    float en = sqrtf(ex*ex + ey*ey);
    float wmin = fminf(9.0f / fmaxf(en, 1e-12f), 1.0f);
    float w  = sqrtf(wmin) * m;
    float w2 = w * w;

    float E[6];
#pragma unroll
    for (int k = 0; k < 6; k++) E[k] = w2*(jp0[k]*jd0 + jp1[k]*jd1);
    float C = w2*(jd0*jd0 + jd1*jd1);
    float cinv = 1.0f / fmaxf(C*onepL, 1.0f);
    float Wv = -w*(jd0*ex + jd1*ey);

    int idx = 0;
#pragma unroll
    for (int k = 0; k < 6; k++)
#pragma unroll
      for (int l = k; l < 6; l++) { acc[idx] += w2*(jp0[k]*jp0[l] + jp1[k]*jp1[l]); idx++; }
#pragma unroll
    for (int k = 0; k < 6; k++) acc[21+k] -= w*(jp0[k]*ex + jp1[k]*ey);
    idx = 27;
#pragma unroll
    for (int k = 0; k < 6; k++)
#pragma unroll
      for (int l = k; l < 6; l++) { acc[idx] += (cinv*E[k])*E[l]; idx++; }
#pragma unroll
    for (int k = 0; k < 6; k++) acc[48+k] += cinv*E[k]*Wv;
  }

  __shared__ float lds[TPB/64][NRED];
  const int lane = threadIdx.x & 63, wvi = threadIdx.x >> 6;
#pragma unroll
  for (int k = 0; k < NRED; k++) {
    float v = wave_red(acc[k]);
    if (lane == 0) lds[wvi][k] = v;
  }
  __syncthreads();
  if (threadIdx.x < NRED) {
    float s = 0.0f;
#pragma unroll
    for (int wq = 0; wq < TPB/64; wq++) s += lds[wq][threadIdx.x];
    partA[((size_t)b*gridDim.x + blockIdx.x)*NRED + threadIdx.x] = s;
  }
}

// ---------------- per-batch 6x6 solve + SE3 + pose compose ----------------
__global__ __launch_bounds__(64) void ksolve(
    const float* __restrict__ partA, int nblk,
    const float* __restrict__ Lc, const float* __restrict__ pose_cur,
    float* __restrict__ pose_new, float* __restrict__ dpose, int N) {
  const int b = blockIdx.x;
  __shared__ float S[NRED];
  const int t = threadIdx.x;
  if (t < NRED) {
    float s = 0.0f;
    for (int j = 0; j < nblk; j++) s += partA[((size_t)b*nblk + j)*NRED + t];
    S[t] = s;
  }
  __syncthreads();
  if (t != 0) return;

  const float invN = 1.0f / (float)N;
  float Bm[6][6], Hs[6][6], g[6], bs[6];
  {
    int idx = 0;
    for (int k = 0; k < 6; k++)
      for (int l = k; l < 6; l++) { float v = S[idx++]*invN; Bm[k][l] = v; Bm[l][k] = v; }
    for (int k = 0; k < 6; k++) g[k] = S[21+k]*invN;
    idx = 27;
    for (int k = 0; k < 6; k++)
      for (int l = k; l < 6; l++) { float v = S[idx++]*invN; Hs[k][l] = v; Hs[l][k] = v; }
    for (int k = 0; k < 6; k++) bs[k] = S[48+k]*invN;
  }
  const float L = Lc[b];
  const float invL = 1.0f / (1.0f + L);
  float left[6][6], right[6];
  for (int k = 0; k < 6; k++) {
    for (int l = 0; l < 6; l++) {
      float v = Bm[k][l] - Hs[k][l]*invL;
      if (k == l) v += Bm[k][k]*L + 1.0f;   // damping + eye
      left[k][l] = v;
    }
    right[k] = g[k] - bs[k]*invL;
  }
  float sv[6];
  for (int k = 0; k < 6; k++) sv[k] = 1.0f / sqrtf(left[k][k] + 10.0f);
  float H[6][7];
  for (int k = 0; k < 6; k++) {
    for (int l = 0; l < 6; l++) H[k][l] = sv[k]*left[k][l]*sv[l];
    H[k][6] = sv[k]*right[k];
  }
  // Gaussian elimination with partial pivoting
  for (int c = 0; c < 6; c++) {
    int piv = c; float mx = fabsf(H[c][c]);
    for (int r = c+1; r < 6; r++) { float a = fabsf(H[r][c]); if (a > mx) { mx = a; piv = r; } }
    if (piv != c)
      for (int cc2 = c; cc2 < 7; cc2++) { float tmp = H[c][cc2]; H[c][cc2] = H[piv][cc2]; H[piv][cc2] = tmp; }
    float ip = 1.0f / H[c][c];
    for (int r = c+1; r < 6; r++) {
      float f = H[r][c]*ip;
      for (int cc2 = c; cc2 < 7; cc2++) H[r][cc2] -= f*H[c][cc2];
    }
  }
  float x[6];
  for (int c = 5; c >= 0; c--) {
    float v = H[c][6];
    for (int cc2 = c+1; cc2 < 6; cc2++) v -= H[c][cc2]*x[cc2];
    x[c] = v / H[c][c];
  }
  float dp[6];
  for (int k = 0; k < 6; k++) { dp[k] = sv[k]*x[k]; dpose[b*6+k] = dp[k]; }

  // SE3 exp
  float tx = dp[0], ty = dp[1], tz = dp[2];
  float wx = dp[3], wy = dp[4], wz = dp[5];
  float Nr = fmaxf(sqrtf(wx*wx + wy*wy + wz*wz), 1e-12f);
  float rx = wx/Nr, ry = wy/Nr, rz = wz/Nr;
  float c_ = cosf(Nr), sn = sinf(Nr);
  float omc = 1.0f - c_;
  float SK[3][3] = {{0.0f,-rz,ry},{rz,0.0f,-rx},{-ry,rx,0.0f}};
  float SK2[3][3];
  for (int i = 0; i < 3; i++)
    for (int j = 0; j < 3; j++) {
      float s2 = 0.0f;
      for (int k = 0; k < 3; k++) s2 += SK[i][k]*SK[k][j];
      SK2[i][j] = s2;
    }
  float rr[3] = {rx, ry, rz};
  float a = (Nr - sn)/Nr, bcoef = omc/Nr;
  float R3[3][3], Jm[3][3];
  for (int i = 0; i < 3; i++)
    for (int j = 0; j < 3; j++) {
      float eye = (i == j) ? 1.0f : 0.0f;
      R3[i][j] = c_*eye + omc*rr[i]*rr[j] + sn*SK[i][j];
      Jm[i][j] = eye + a*SK2[i][j] + bcoef*SK[i][j];
    }
  float T3[3];
  for (int i = 0; i < 3; i++) T3[i] = Jm[i][0]*tx + Jm[i][1]*ty + Jm[i][2]*tz;
  float Pc[16];
  for (int i = 0; i < 16; i++) Pc[i] = pose_cur[b*16+i];
  float Pn[16];
  for (int i = 0; i < 3; i++)
    for (int j = 0; j < 4; j++)
      Pn[i*4+j] = R3[i][0]*Pc[j] + R3[i][1]*Pc[4+j] + R3[i][2]*Pc[8+j] + T3[i]*Pc[12+j];
  for (int j = 0; j < 4; j++) Pn[12+j] = Pc[12+j];
  for (int i = 0; i < 16; i++) pose_new[b*16+i] = Pn[i];
}

// ---------------- Pass B: delta-disp proposal + r1/r2 reduction ----------------
__global__ __launch_bounds__(TPB) void kpassB(
    const float* __restrict__ pts, const float* __restrict__ disp_cur,
    const float* __restrict__ mask,
    const float* __restrict__ Kin, const float* __restrict__ Kiin,
    const float* __restrict__ pose_cur, const float* __restrict__ pose_new,
    const float* __restrict__ Lc, const float* __restrict__ dpose,
    float* __restrict__ prop, float* __restrict__ partB, int N) {
  const int b = blockIdx.y;
  float Kc[9], Ki[9], P[12], Pn[12], dp[6];
#pragma unroll
  for (int i = 0; i < 9; i++) { Kc[i] = Kin[b*9+i]; Ki[i] = Kiin[b*9+i]; }
#pragma unroll
  for (int i = 0; i < 12; i++) { P[i] = pose_cur[b*16+i]; Pn[i] = pose_new[b*16+i]; }
#pragma unroll
  for (int i = 0; i < 6; i++) dp[i] = dpose[b*6+i];
  const float Lval = Lc[b];
  const float onepL = 1.0f + Lval;
  const float invL = 1.0f / onepL;
  const float fx = Kc[0], fy = Kc[4];

  float r1a = 0.0f, r2a = 0.0f, msa = 0.0f;
  const size_t bN = (size_t)b * N;
  const float* px1 = pts + (size_t)b*4*N;
  const float* py1 = px1 + N;
  const float* px2 = px1 + 2*(size_t)N;
  const float* py2 = px1 + 3*(size_t)N;

  for (int n = blockIdx.x*TPB + threadIdx.x; n < N; n += gridDim.x*TPB) {
    float x1 = px1[n], y1 = py1[n], x2 = px2[n], y2 = py2[n];
    float d = disp_cur[bN+n];
    float m = mask[bN+n];

    // recompute E, cinv, Wv (entry disp/pose)
    float depth = 1.0f / d;
    float pxx = (Ki[0]*x1 + Ki[1]*y1 + Ki[2]) * depth;
    float pyy = (Ki[3]*x1 + Ki[4]*y1 + Ki[5]) * depth;
    float pzz = (Ki[6]*x1 + Ki[7]*y1 + Ki[8]) * depth;
    float X = P[0]*pxx + P[1]*pyy + P[2]*pzz + P[3];
    float Y = P[4]*pxx + P[5]*pyy + P[6]*pzz + P[7];
    float Z = P[8]*pxx + P[9]*pyy + P[10]*pzz + P[11];
    float q0 = Kc[0]*X + Kc[1]*Y + Kc[2]*Z;
    float q1 = Kc[3]*X + Kc[4]*Y + Kc[5]*Z;
    float q2 = Kc[6]*X + Kc[7]*Y + Kc[8]*Z;
    float iZc = 1.0f / fmaxf(q2, 0.01f);
    float ex = x2 - q0*iZc;
    float ey = y2 - q1*iZc;
    float iZ = 1.0f / fmaxf(Z, 1e-12f);
    float iZ2 = iZ*iZ;

    float jp0[6], jp1[6];
    jp0[0] = -(fx*iZ);  jp0[1] = 0.0f;       jp0[2] = fx*X*iZ2;
    jp0[3] = fx*X*Y*iZ2; jp0[4] = -(fx + fx*X*X*iZ2); jp0[5] = fx*Y*iZ;
    jp1[0] = 0.0f;      jp1[1] = -(fy*iZ);   jp1[2] = fy*Y*iZ2;
    jp1[3] = fy + fy*Y*Y*iZ2; jp1[4] = -(fy*X*Y*iZ2); jp1[5] = -(fy*X*iZ);

    float DD = -depth;
    float dx = X - P[3], dy = Y - P[7], dz = Z - P[11];
    float jd0 = -((fx*iZ)*(DD*dx) - (fx*X*iZ2)*(DD*dz));
    float jd1 = -((fy*iZ)*(DD*dy) - (fy*Y*iZ2)*(DD*dz));

    float en = sqrtf(ex*ex + ey*ey);
    float wmin = fminf(9.0f / fmaxf(en, 1e-12f), 1.0f);
    float w  = sqrtf(wmin) * m;
    float w2 = w * w;

    float dotE = 0.0f;
#pragma unroll
    for (int k = 0; k < 6; k++) {
      float Ek = w2*(jp0[k]*jd0 + jp1[k]*jd1);
      dotE += Ek * dp[k];
    }
    float C = w2*(jd0*jd0 + jd1*jd1);
    float cinv = 1.0f / fmaxf(C*onepL, 1.0f);
    float Wv = -w*(jd0*ex + jd1*ey);

    float dnew = d + cinv*(Wv - dotE*invL);
    dnew = fminf(fmaxf(dnew, 0.01f), 10.0f);
    prop[bN+n] = dnew;

    float n1 = reproj_norm(x1, y1, x2, y2, dnew, Pn, Kc, Ki);
    float n2 = reproj_norm(x1, y1, x2, y2, d,    P,  Kc, Ki);
    r1a += n1*m; r2a += n2*m; msa += m;
  }

  __shared__ float lds[TPB/64][3];
  const int lane = threadIdx.x & 63, wvi = threadIdx.x >> 6;
  float v0 = wave_red(r1a), v1 = wave_red(r2a), v2 = wave_red(msa);
  if (lane == 0) { lds[wvi][0] = v0; lds[wvi][1] = v1; lds[wvi][2] = v2; }
  __syncthreads();
  if (threadIdx.x < 3) {
    float s = 0.0f;
#pragma unroll
    for (int wq = 0; wq < TPB/64; wq++) s += lds[wq][threadIdx.x];
    partB[((size_t)b*gridDim.x + blockIdx.x)*3 + threadIdx.x] = s;
  }
}

// ---------------- accept/reject + pose/L/flag update ----------------
__global__ __launch_bounds__(256) void kupdate(
    int iter, const float* __restrict__ partB, int nblk,
    const float* __restrict__ pose_in, const float* __restrict__ L_in,
    float* __restrict__ pose_cur, const float* __restrict__ pose_new,
    float* __restrict__ Lc, float* __restrict__ flags, int B) {
  const int t = threadIdx.x;
  if (iter == 0) {
    if (t < B*16) pose_cur[t] = pose_in[t];
    if (t < B) { Lc[t] = L_in[t]; flags[t] = 0.0f; }
    return;
  }
  __shared__ float sM[16];
  if (t < B) {
    float r1 = 0.0f, r2 = 0.0f, ms = 0.0f;
    for (int j = 0; j < nblk; j++) {
      const float* p = partB + ((size_t)t*nblk + j)*3;
      r1 += p[0]; r2 += p[1]; ms += p[2];
    }
    float M = ((r1/ms) < (r2/ms)) ? 1.0f : 0.0f;
    sM[t] = M;
    flags[t] = M;
    float L = Lc[t];
    L = (M != 0.0f) ? L*0.5f : L*5.0f;
    Lc[t] = fminf(fmaxf(L, 0.01f), 1000000.0f);
  }
  __syncthreads();
  if (t < B*16) {
    int b = t >> 4;
    if (sM[b] != 0.0f) pose_cur[t] = pose_new[t];
  }
}

// ---------------- final output ----------------
__global__ __launch_bounds__(TPB) void kout(
    const float* __restrict__ pose_cur, const float* __restrict__ flags,
    const float* __restrict__ prop, float* __restrict__ dout, int N, int B) {
  const int b = blockIdx.y;
  if (blockIdx.x == 0 && threadIdx.x < 16)
    dout[b*16 + threadIdx.x] = pose_cur[b*16 + threadIdx.x];
  if (flags[b] == 0.0f) return;  // disp_cur already resides in dout's disp region
  float* dd = dout + B*16;
  const size_t bN = (size_t)b * N;
  for (int n = blockIdx.x*TPB + threadIdx.x; n < N; n += gridDim.x*TPB)
    dd[bN+n] = prop[bN+n];
}

extern "C" void kernel_launch(void* const* d_in, const int* in_sizes, int n_in,
                              void* d_out, int out_size, void* d_ws, size_t ws_size,
                              hipStream_t stream) {
  const float* pts   = (const float*)d_in[0];
  const float* disp0 = (const float*)d_in[1];
  const float* pose0 = (const float*)d_in[2];
  const float* Kin   = (const float*)d_in[3];
  const float* Kiin  = (const float*)d_in[4];
  const float* mask  = (const float*)d_in[5];
  const float* L0    = (const float*)d_in[6];

  const int B = in_sizes[6];            // 8
  const int N = in_sizes[1] / B;        // 131072
  const size_t BN = (size_t)B * N;

  float* out      = (float*)d_out;
  float* disp_cur = out + B*16;         // output disp region doubles as state

  float* ws       = (float*)d_ws;
  float* prop     = ws;                                  // BN
  float* partA    = prop + BN;                           // B*BLKA*NRED
  float* partB    = partA + (size_t)B*BLKA*NRED;         // B*BLKA*3
  float* pose_cur = partB + (size_t)B*BLKA*3;            // B*16
  float* pose_new = pose_cur + (size_t)B*16;             // B*16
  float* Lc       = pose_new + (size_t)B*16;             // B
  float* dpose    = Lc + B;                              // B*6
  float* flags    = dpose + (size_t)B*6;                 // B

  dim3 gridBig(BLKA, B), blk(TPB);
  for (int it = 0; it < 4; ++it) {
    kupdate<<<1, 256, 0, stream>>>(it, partB, BLKA, pose0, L0,
                                   pose_cur, pose_new, Lc, flags, B);
    kpassA<<<gridBig, blk, 0, stream>>>(pts, (it == 0) ? disp0 : disp_cur, prop,
                                        mask, Kin, Kiin, disp_cur, pose_cur,
                                        Lc, flags, partA, N);
    ksolve<<<dim3(B), dim3(64), 0, stream>>>(partA, BLKA, Lc, pose_cur,
                                             pose_new, dpose, N);
    kpassB<<<gridBig, blk, 0, stream>>>(pts, disp_cur, mask, Kin, Kiin,
                                        pose_cur, pose_new, Lc, dpose,
                                        prop, partB, N);
  }
  kupdate<<<1, 256, 0, stream>>>(4, partB, BLKA, pose0, L0,
                                 pose_cur, pose_new, Lc, flags, B);
  kout<<<gridBig, blk, 0, stream>>>(pose_cur, flags, prop, out, N, B);
}

// Round 3
// 285.357 us; speedup vs baseline: 1.2247x; 1.2247x over previous
//
#include <hip/hip_runtime.h>
#include <math.h>

// Geometric BA (LM) — 4 iterations, B=8, N=131072.
// Round 2 (resubmit — previous bench was a GPU-acquisition timeout, no data):
// collapse 18 dispatches -> 9. The tiny per-batch kernels (accept decision,
// 6x6 solve) are folded into the big per-point passes as redundant per-block
// prologues; persistent per-iter state (pose, L) lives in parity
// double-buffered ws slots written only by block (0,b).
//   per iter:  kA (accept-prologue + Jacobians + 54-red)
//              kB (solve-prologue + delta-disp + r1/r2-red)
//   final   :  kF (accept-prologue + pose/disp output)
// All reduction orders match the round-1 passing version bit-for-bit.

constexpr int TPB  = 256;
constexpr int BLKA = 64;   // blocks per batch for the big per-point kernels
constexpr int NRED = 54;   // Bm(21) + g(6) + Hsc(21) + bsc(6)

__device__ __forceinline__ float wave_red(float v) {
#pragma unroll
  for (int m = 32; m; m >>= 1) v += __shfl_xor(v, m, 64);
  return v;
}

__device__ __forceinline__ float reproj_norm(
    float x1, float y1, float x2, float y2, float d,
    const float* P, const float* Kc, const float* Ki) {
  float depth = 1.0f / fmaxf(d, 0.01f);
  float pxx = (Ki[0]*x1 + Ki[1]*y1 + Ki[2]) * depth;
  float pyy = (Ki[3]*x1 + Ki[4]*y1 + Ki[5]) * depth;
  float pzz = (Ki[6]*x1 + Ki[7]*y1 + Ki[8]) * depth;
  float X = P[0]*pxx + P[1]*pyy + P[2]*pzz + P[3];
  float Y = P[4]*pxx + P[5]*pyy + P[6]*pzz + P[7];
  float Z = P[8]*pxx + P[9]*pyy + P[10]*pzz + P[11];
  float q0 = Kc[0]*X + Kc[1]*Y + Kc[2]*Z;
  float q1 = Kc[3]*X + Kc[4]*Y + Kc[5]*Z;
  float q2 = Kc[6]*X + Kc[7]*Y + Kc[8]*Z;
  float iZc = 1.0f / fmaxf(q2, 0.01f);
  float ex = x2 - q0*iZc, ey = y2 - q1*iZc;
  return sqrtf(ex*ex + ey*ey);
}

// Accept decision (same math/order as round-1 kupdate). Returns M.
__device__ __forceinline__ float accept_M(const float* __restrict__ partB,
                                          int b) {
  float r1 = 0.0f, r2 = 0.0f, ms = 0.0f;
  for (int j = 0; j < BLKA; j++) {
    const float* p = partB + ((size_t)b*BLKA + j)*3;
    r1 += p[0]; r2 += p[1]; ms += p[2];
  }
  return ((r1/ms) < (r2/ms)) ? 1.0f : 0.0f;
}

// ---------------- Pass A: accept-prologue + Jacobians + 54-red ----------------
__global__ __launch_bounds__(TPB) void kA(
    int it,
    const float* __restrict__ pts, const float* __restrict__ disp_src,
    const float* __restrict__ prop, const float* __restrict__ mask,
    const float* __restrict__ Kin, const float* __restrict__ Kiin,
    float* __restrict__ disp_cur,
    const float* __restrict__ pose0, const float* __restrict__ L0,
    const float* __restrict__ partB, const float* __restrict__ pose_new_ws,
    float* __restrict__ pose_slot_w, const float* __restrict__ pose_slot_r,
    float* __restrict__ L_slot_w, const float* __restrict__ L_slot_r,
    float* __restrict__ partA, int N) {
  const int b = blockIdx.y;

  __shared__ float sP[16];
  __shared__ float sMeta[2];   // [0]=fsel, [1]=Lval
  if (threadIdx.x == 0) {
    float P[16], Lv, fs;
    if (it == 0) {
      for (int i = 0; i < 16; i++) P[i] = pose0[b*16+i];
      Lv = L0[b]; fs = 0.0f;
    } else {
      float M = accept_M(partB, b);
      fs = M;
      float Lp = L_slot_r[b];
      float Ln = (M != 0.0f) ? Lp*0.5f : Lp*5.0f;
      Lv = fminf(fmaxf(Ln, 0.01f), 1000000.0f);
      for (int i = 0; i < 16; i++)
        P[i] = (M != 0.0f) ? pose_new_ws[b*16+i] : pose_slot_r[b*16+i];
    }
    for (int i = 0; i < 16; i++) sP[i] = P[i];
    sMeta[0] = fs; sMeta[1] = Lv;
    if (blockIdx.x == 0) {
      for (int i = 0; i < 16; i++) pose_slot_w[b*16+i] = P[i];
      L_slot_w[b] = Lv;
    }
  }
  __syncthreads();

  float Kc[9], Ki[9], P[12];
#pragma unroll
  for (int i = 0; i < 9; i++) { Kc[i] = Kin[b*9+i]; Ki[i] = Kiin[b*9+i]; }
#pragma unroll
  for (int i = 0; i < 12; i++) P[i] = sP[i];
  const float onepL = 1.0f + sMeta[1];
  const float fsel = sMeta[0];
  const float fx = Kc[0], fy = Kc[4];

  float acc[NRED];
#pragma unroll
  for (int k = 0; k < NRED; k++) acc[k] = 0.0f;

  const size_t bN = (size_t)b * N;
  const float* px1 = pts + (size_t)b*4*N;
  const float* py1 = px1 + N;
  const float* px2 = px1 + 2*(size_t)N;
  const float* py2 = px1 + 3*(size_t)N;

  for (int n = blockIdx.x*TPB + threadIdx.x; n < N; n += gridDim.x*TPB) {
    float x1 = px1[n], y1 = py1[n], x2 = px2[n], y2 = py2[n];
    float d = disp_src[bN+n];
    if (fsel != 0.0f) d = prop[bN+n];
    disp_cur[bN+n] = d;
    float m = mask[bN+n];

    float depth = 1.0f / d;
    float pxx = (Ki[0]*x1 + Ki[1]*y1 + Ki[2]) * depth;
    float pyy = (Ki[3]*x1 + Ki[4]*y1 + Ki[5]) * depth;
    float pzz = (Ki[6]*x1 + Ki[7]*y1 + Ki[8]) * depth;
    float X = P[0]*pxx + P[1]*pyy + P[2]*pzz + P[3];
    float Y = P[4]*pxx + P[5]*pyy + P[6]*pzz + P[7];
    float Z = P[8]*pxx + P[9]*pyy + P[10]*pzz + P[11];
    float q0 = Kc[0]*X + Kc[1]*Y + Kc[2]*Z;
    float q1 = Kc[3]*X + Kc[4]*Y + Kc[5]*Z;
    float q2 = Kc[6]*X + Kc[7]*Y + Kc[8]*Z;
    float iZc = 1.0f / fmaxf(q2, 0.01f);
    float ex = x2 - q0*iZc;
    float ey = y2 - q1*iZc;
    float iZ = 1.0f / fmaxf(Z, 1e-12f);
    float iZ2 = iZ*iZ;

    float jp0[6], jp1[6];
    jp0[0] = -(fx*iZ);  jp0[1] = 0.0f;       jp0[2] = fx*X*iZ2;
    jp0[3] = fx*X*Y*iZ2; jp0[4] = -(fx + fx*X*X*iZ2); jp0[5] = fx*Y*iZ;
    jp1[0] = 0.0f;      jp1[1] = -(fy*iZ);   jp1[2] = fy*Y*iZ2;
    jp1[3] = fy + fy*Y*Y*iZ2; jp1[4] = -(fy*X*Y*iZ2); jp1[5] = -(fy*X*iZ);

    float DD = -depth;
    float dx = X - P[3], dy = Y - P[7], dz = Z - P[11];
    float jd0 = -((fx*iZ)*(DD*dx) - (fx*X*iZ2)*(DD*dz));
    float jd1 = -((fy*iZ)*(DD*dy) - (fy*Y*iZ2)*(DD*dz));

    float en = sqrtf(ex*ex + ey*ey);
    float wmin = fminf(9.0f / fmaxf(en, 1e-12f), 1.0f);
    float w  = sqrtf(wmin) * m;
    float w2 = w * w;

    float E[6];
#pragma unroll
    for (int k = 0; k < 6; k++) E[k] = w2*(jp0[k]*jd0 + jp1[k]*jd1);
    float C = w2*(jd0*jd0 + jd1*jd1);
    float cinv = 1.0f / fmaxf(C*onepL, 1.0f);
    float Wv = -w*(jd0*ex + jd1*ey);

    int idx = 0;
#pragma unroll
    for (int k = 0; k < 6; k++)
#pragma unroll
      for (int l = k; l < 6; l++) { acc[idx] += w2*(jp0[k]*jp0[l] + jp1[k]*jp1[l]); idx++; }
#pragma unroll
    for (int k = 0; k < 6; k++) acc[21+k] -= w*(jp0[k]*ex + jp1[k]*ey);
    idx = 27;
#pragma unroll
    for (int k = 0; k < 6; k++)
#pragma unroll
      for (int l = k; l < 6; l++) { acc[idx] += (cinv*E[k])*E[l]; idx++; }
#pragma unroll
    for (int k = 0; k < 6; k++) acc[48+k] += cinv*E[k]*Wv;
  }

  __shared__ float lds[TPB/64][NRED];
  const int lane = threadIdx.x & 63, wvi = threadIdx.x >> 6;
#pragma unroll
  for (int k = 0; k < NRED; k++) {
    float v = wave_red(acc[k]);
    if (lane == 0) lds[wvi][k] = v;
  }
  __syncthreads();
  if (threadIdx.x < NRED) {
    float s = 0.0f;
#pragma unroll
    for (int wq = 0; wq < TPB/64; wq++) s += lds[wq][threadIdx.x];
    partA[((size_t)b*gridDim.x + blockIdx.x)*NRED + threadIdx.x] = s;
  }
}

// ---------------- Pass B: solve-prologue + delta-disp + r1/r2-red ----------------
__global__ __launch_bounds__(TPB) void kB(
    const float* __restrict__ pts, const float* __restrict__ disp_cur,
    const float* __restrict__ mask,
    const float* __restrict__ Kin, const float* __restrict__ Kiin,
    const float* __restrict__ pose_slot, const float* __restrict__ L_slot,
    const float* __restrict__ partA,
    float* __restrict__ pose_new_ws,
    float* __restrict__ prop, float* __restrict__ partB, int N) {
  const int b = blockIdx.y;
  const float L = L_slot[b];

  __shared__ float S[NRED];
  __shared__ float sPn[16];
  __shared__ float sdp[6];
  if (threadIdx.x < NRED) {
    float s = 0.0f;
    for (int j = 0; j < BLKA; j++)
      s += partA[((size_t)b*BLKA + j)*NRED + threadIdx.x];
    S[threadIdx.x] = s;
  }
  __syncthreads();
  if (threadIdx.x == 0) {
    const float invN = 1.0f / (float)N;
    float Bm[6][6], Hs[6][6], g[6], bs[6];
    {
      int idx = 0;
      for (int k = 0; k < 6; k++)
        for (int l = k; l < 6; l++) { float v = S[idx++]*invN; Bm[k][l] = v; Bm[l][k] = v; }
      for (int k = 0; k < 6; k++) g[k] = S[21+k]*invN;
      idx = 27;
      for (int k = 0; k < 6; k++)
        for (int l = k; l < 6; l++) { float v = S[idx++]*invN; Hs[k][l] = v; Hs[l][k] = v; }
      for (int k = 0; k < 6; k++) bs[k] = S[48+k]*invN;
    }
    const float invL = 1.0f / (1.0f + L);
    float left[6][6], right[6];
    for (int k = 0; k < 6; k++) {
      for (int l = 0; l < 6; l++) {
        float v = Bm[k][l] - Hs[k][l]*invL;
        if (k == l) v += Bm[k][k]*L + 1.0f;
        left[k][l] = v;
      }
      right[k] = g[k] - bs[k]*invL;
    }
    float sv[6];
    for (int k = 0; k < 6; k++) sv[k] = 1.0f / sqrtf(left[k][k] + 10.0f);
    float H[6][7];
    for (int k = 0; k < 6; k++) {
      for (int l = 0; l < 6; l++) H[k][l] = sv[k]*left[k][l]*sv[l];
      H[k][6] = sv[k]*right[k];
    }
    for (int c = 0; c < 6; c++) {
      int piv = c; float mx = fabsf(H[c][c]);
      for (int r = c+1; r < 6; r++) { float a = fabsf(H[r][c]); if (a > mx) { mx = a; piv = r; } }
      if (piv != c)
        for (int cc2 = c; cc2 < 7; cc2++) { float tmp = H[c][cc2]; H[c][cc2] = H[piv][cc2]; H[piv][cc2] = tmp; }
      float ip = 1.0f / H[c][c];
      for (int r = c+1; r < 6; r++) {
        float f = H[r][c]*ip;
        for (int cc2 = c; cc2 < 7; cc2++) H[r][cc2] -= f*H[c][cc2];
      }
    }
    float x[6];
    for (int c = 5; c >= 0; c--) {
      float v = H[c][6];
      for (int cc2 = c+1; cc2 < 6; cc2++) v -= H[c][cc2]*x[cc2];
      x[c] = v / H[c][c];
    }
    float dp[6];
    for (int k = 0; k < 6; k++) { dp[k] = sv[k]*x[k]; sdp[k] = dp[k]; }

    // SE3 exp + compose
    float tx = dp[0], ty = dp[1], tz = dp[2];
    float wx = dp[3], wy = dp[4], wz = dp[5];
    float Nr = fmaxf(sqrtf(wx*wx + wy*wy + wz*wz), 1e-12f);
    float rx = wx/Nr, ry = wy/Nr, rz = wz/Nr;
    float c_ = cosf(Nr), sn = sinf(Nr);
    float omc = 1.0f - c_;
    float SK[3][3] = {{0.0f,-rz,ry},{rz,0.0f,-rx},{-ry,rx,0.0f}};
    float SK2[3][3];
    for (int i = 0; i < 3; i++)
      for (int j = 0; j < 3; j++) {
        float s2 = 0.0f;
        for (int k = 0; k < 3; k++) s2 += SK[i][k]*SK[k][j];
        SK2[i][j] = s2;
      }
    float rr[3] = {rx, ry, rz};
    float a = (Nr - sn)/Nr, bcoef = omc/Nr;
    float R3[3][3], Jm[3][3];
    for (int i = 0; i < 3; i++)
      for (int j = 0; j < 3; j++) {
        float eye = (i == j) ? 1.0f : 0.0f;
        R3[i][j] = c_*eye + omc*rr[i]*rr[j] + sn*SK[i][j];
        Jm[i][j] = eye + a*SK2[i][j] + bcoef*SK[i][j];
      }
    float T3[3];
    for (int i = 0; i < 3; i++) T3[i] = Jm[i][0]*tx + Jm[i][1]*ty + Jm[i][2]*tz;
    float Pc[16];
    for (int i = 0; i < 16; i++) Pc[i] = pose_slot[b*16+i];
    float Pn[16];
    for (int i = 0; i < 3; i++)
      for (int j = 0; j < 4; j++)
        Pn[i*4+j] = R3[i][0]*Pc[j] + R3[i][1]*Pc[4+j] + R3[i][2]*Pc[8+j] + T3[i]*Pc[12+j];
    for (int j = 0; j < 4; j++) Pn[12+j] = Pc[12+j];
    for (int i = 0; i < 16; i++) sPn[i] = Pn[i];
    if (blockIdx.x == 0)
      for (int i = 0; i < 16; i++) pose_new_ws[b*16+i] = Pn[i];
  }
  __syncthreads();

  float Kc[9], Ki[9], P[12], Pn[12], dp[6];
#pragma unroll
  for (int i = 0; i < 9; i++) { Kc[i] = Kin[b*9+i]; Ki[i] = Kiin[b*9+i]; }
#pragma unroll
  for (int i = 0; i < 12; i++) { P[i] = pose_slot[b*16+i]; Pn[i] = sPn[i]; }
#pragma unroll
  for (int i = 0; i < 6; i++) dp[i] = sdp[i];
  const float onepL = 1.0f + L;
  const float invL = 1.0f / onepL;
  const float fx = Kc[0], fy = Kc[4];

  float r1a = 0.0f, r2a = 0.0f, msa = 0.0f;
  const size_t bN = (size_t)b * N;
  const float* px1 = pts + (size_t)b*4*N;
  const float* py1 = px1 + N;
  const float* px2 = px1 + 2*(size_t)N;
  const float* py2 = px1 + 3*(size_t)N;

  for (int n = blockIdx.x*TPB + threadIdx.x; n < N; n += gridDim.x*TPB) {
    float x1 = px1[n], y1 = py1[n], x2 = px2[n], y2 = py2[n];
    float d = disp_cur[bN+n];
    float m = mask[bN+n];

    float depth = 1.0f / d;
    float pxx = (Ki[0]*x1 + Ki[1]*y1 + Ki[2]) * depth;
    float pyy = (Ki[3]*x1 + Ki[4]*y1 + Ki[5]) * depth;
    float pzz = (Ki[6]*x1 + Ki[7]*y1 + Ki[8]) * depth;
    float X = P[0]*pxx + P[1]*pyy + P[2]*pzz + P[3];
    float Y = P[4]*pxx + P[5]*pyy + P[6]*pzz + P[7];
    float Z = P[8]*pxx + P[9]*pyy + P[10]*pzz + P[11];
    float q0 = Kc[0]*X + Kc[1]*Y + Kc[2]*Z;
    float q1 = Kc[3]*X + Kc[4]*Y + Kc[5]*Z;
    float q2 = Kc[6]*X + Kc[7]*Y + Kc[8]*Z;
    float iZc = 1.0f / fmaxf(q2, 0.01f);
    float ex = x2 - q0*iZc;
    float ey = y2 - q1*iZc;
    float iZ = 1.0f / fmaxf(Z, 1e-12f);
    float iZ2 = iZ*iZ;

    float jp0[6], jp1[6];
    jp0[0] = -(fx*iZ);  jp0[1] = 0.0f;       jp0[2] = fx*X*iZ2;
    jp0[3] = fx*X*Y*iZ2; jp0[4] = -(fx + fx*X*X*iZ2); jp0[5] = fx*Y*iZ;
    jp1[0] = 0.0f;      jp1[1] = -(fy*iZ);   jp1[2] = fy*Y*iZ2;
    jp1[3] = fy + fy*Y*Y*iZ2; jp1[4] = -(fy*X*Y*iZ2); jp1[5] = -(fy*X*iZ);

    float DD = -depth;
    float dx = X - P[3], dy = Y - P[7], dz = Z - P[11];
    float jd0 = -((fx*iZ)*(DD*dx) - (fx*X*iZ2)*(DD*dz));
    float jd1 = -((fy*iZ)*(DD*dy) - (fy*Y*iZ2)*(DD*dz));

    float en = sqrtf(ex*ex + ey*ey);
    float wmin = fminf(9.0f / fmaxf(en, 1e-12f), 1.0f);
    float w  = sqrtf(wmin) * m;
    float w2 = w * w;

    float dotE = 0.0f;
#pragma unroll
    for (int k = 0; k < 6; k++) {
      float Ek = w2*(jp0[k]*jd0 + jp1[k]*jd1);
      dotE += Ek * dp[k];
    }
    float C = w2*(jd0*jd0 + jd1*jd1);
    float cinv = 1.0f / fmaxf(C*onepL, 1.0f);
    float Wv = -w*(jd0*ex + jd1*ey);

    float dnew = d + cinv*(Wv - dotE*invL);
    dnew = fminf(fmaxf(dnew, 0.01f), 10.0f);
    prop[bN+n] = dnew;

    float n1 = reproj_norm(x1, y1, x2, y2, dnew, Pn, Kc, Ki);
    float n2 = reproj_norm(x1, y1, x2, y2, d,    P,  Kc, Ki);
    r1a += n1*m; r2a += n2*m; msa += m;
  }

  __shared__ float lds[TPB/64][3];
  const int lane = threadIdx.x & 63, wvi = threadIdx.x >> 6;
  float v0 = wave_red(r1a), v1 = wave_red(r2a), v2 = wave_red(msa);
  if (lane == 0) { lds[wvi][0] = v0; lds[wvi][1] = v1; lds[wvi][2] = v2; }
  __syncthreads();
  if (threadIdx.x < 3) {
    float s = 0.0f;
#pragma unroll
    for (int wq = 0; wq < TPB/64; wq++) s += lds[wq][threadIdx.x];
    partB[((size_t)b*gridDim.x + blockIdx.x)*3 + threadIdx.x] = s;
  }
}

// ---------------- Final: accept-prologue + pose/disp output ----------------
__global__ __launch_bounds__(TPB) void kF(
    const float* __restrict__ partB,
    const float* __restrict__ pose_slot, const float* __restrict__ pose_new_ws,
    const float* __restrict__ prop, float* __restrict__ dout, int N, int B) {
  const int b = blockIdx.y;
  __shared__ float sM[1];
  if (threadIdx.x == 0) sM[0] = accept_M(partB, b);
  __syncthreads();
  const float M = sM[0];

  if (blockIdx.x == 0 && threadIdx.x < 16) {
    float v = (M != 0.0f) ? pose_new_ws[b*16+threadIdx.x] : pose_slot[b*16+threadIdx.x];
    dout[b*16 + threadIdx.x] = v;
  }
  if (M == 0.0f) return;  // disp_cur already resides in dout's disp region
  float* dd = dout + B*16;
  const size_t bN = (size_t)b * N;
  for (int n = blockIdx.x*TPB + threadIdx.x; n < N; n += gridDim.x*TPB)
    dd[bN+n] = prop[bN+n];
}

extern "C" void kernel_launch(void* const* d_in, const int* in_sizes, int n_in,
                              void* d_out, int out_size, void* d_ws, size_t ws_size,
                              hipStream_t stream) {
  const float* pts   = (const float*)d_in[0];
  const float* disp0 = (const float*)d_in[1];
  const float* pose0 = (const float*)d_in[2];
  const float* Kin   = (const float*)d_in[3];
  const float* Kiin  = (const float*)d_in[4];
  const float* mask  = (const float*)d_in[5];
  const float* L0    = (const float*)d_in[6];

  const int B = in_sizes[6];            // 8
  const int N = in_sizes[1] / B;        // 131072
  const size_t BN = (size_t)B * N;

  float* out      = (float*)d_out;
  float* disp_cur = out + B*16;         // output disp region doubles as state

  float* ws        = (float*)d_ws;
  float* prop      = ws;                                  // BN
  float* partA     = prop + BN;                           // B*BLKA*NRED
  float* partB     = partA + (size_t)B*BLKA*NRED;         // B*BLKA*3
  float* pose_slots= partB + (size_t)B*BLKA*3;            // 2*B*16
  float* pose_new  = pose_slots + (size_t)2*B*16;         // B*16
  float* L_slots   = pose_new + (size_t)B*16;             // 2*B

  dim3 gridBig(BLKA, B), blk(TPB);
  for (int it = 0; it < 4; ++it) {
    float* ps_w = pose_slots + (size_t)(it & 1) * B * 16;
    const float* ps_r = pose_slots + (size_t)((it + 1) & 1) * B * 16;
    float* Ls_w = L_slots + (size_t)(it & 1) * B;
    const float* Ls_r = L_slots + (size_t)((it + 1) & 1) * B;

    kA<<<gridBig, blk, 0, stream>>>(it, pts, (it == 0) ? disp0 : disp_cur, prop,
                                    mask, Kin, Kiin, disp_cur, pose0, L0,
                                    partB, pose_new, ps_w, ps_r, Ls_w, Ls_r,
                                    partA, N);
    kB<<<gridBig, blk, 0, stream>>>(pts, disp_cur, mask, Kin, Kiin,
                                    ps_w, Ls_w, partA, pose_new,
                                    prop, partB, N);
  }
  // state after iter 3 lives in slot (3&1)=1
  kF<<<gridBig, blk, 0, stream>>>(partB, pose_slots + (size_t)1*B*16, pose_new,
                                  prop, out, N, B);
}